// Round 1
// baseline (448.335 us; speedup 1.0000x reference)
//
#include <hip/hip_runtime.h>

// =============================================================================
// QuantumContrastiveModel — mathematical reduction:
//   StronglyEntanglingLayers is a fixed 16x16 UNITARY U(theta) applied to BOTH
//   states; fidelity |<U va|U vb>|^2 = (va.vb)^2 — the circuit cancels, theta
//   is unused. With u = tanh(relu(x@W1+b1)@W2+b2):
//     fid = clip( (ua.ub)^2 / (max(|ua|,1e-8)*max(|ub|,1e-8))^2, 0, 1 )
//   Remaining work: fused GEMM (2B x 784 x 64) in bf16 MFMA + tiny fp32 tail.
//   Roofline: 411 MB image reads -> ~65 us @ 6.3 TB/s.
// =============================================================================

#define KDIM   784
#define HDIM   64
#define VDIM   16
#define KSTEPS 25                        // ceil(784/32); last step zero-padded
#define W1S_ELEMS (KSTEPS * 4 * 64 * 8)  // 51200 bf16 in B-fragment order
#define W1S_BYTES (W1S_ELEMS * 2)        // 102400 bytes

typedef float  f32x4  __attribute__((ext_vector_type(4)));
typedef short  bf16x8 __attribute__((ext_vector_type(8)));

__device__ __forceinline__ unsigned short f2bf(float f) {
  unsigned u = __float_as_uint(f);
  u += 0x7fffu + ((u >> 16) & 1u);       // round-to-nearest-even
  return (unsigned short)(u >> 16);
}

__device__ __forceinline__ bf16x8 cvt8(f32x4 lo, f32x4 hi) {
  bf16x8 r;
  r[0] = (short)f2bf(lo[0]); r[1] = (short)f2bf(lo[1]);
  r[2] = (short)f2bf(lo[2]); r[3] = (short)f2bf(lo[3]);
  r[4] = (short)f2bf(hi[0]); r[5] = (short)f2bf(hi[1]);
  r[6] = (short)f2bf(hi[2]); r[7] = (short)f2bf(hi[3]);
  return r;
}

__device__ __forceinline__ float tanh_fast(float x) {
  float e = __expf(2.0f * x);
  return 1.0f - 2.0f / (e + 1.0f);       // exact limits at +-inf
}

// --- prep: W1 (784x64 f32) -> bf16 in MFMA B-fragment order, K padded to 800;
//           W2 (64x16) -> transposed (16x64) f32.
__global__ __launch_bounds__(256)
void prep_kernel(const float* __restrict__ W1, const float* __restrict__ W2,
                 unsigned short* __restrict__ w1s, float* __restrict__ w2t) {
  int tid = blockIdx.x * 256 + threadIdx.x;
  if (tid < W1S_ELEMS) {
    int j  = tid & 7;            // element within 8-wide fragment
    int l  = (tid >> 3) & 63;    // lane
    int st = tid >> 9;           // s*4 + t
    int s  = st >> 2;
    int t  = st & 3;
    int k  = s * 32 + (l >> 4) * 8 + j;   // B[k][n]: k = quad*8+j
    int n  = t * 16 + (l & 15);           //          n = lane&15
    float v = (k < KDIM) ? W1[k * HDIM + n] : 0.0f;
    w1s[tid] = f2bf(v);
  }
  if (tid < HDIM * VDIM) {
    int c = tid >> 6;            // 0..15
    int k = tid & 63;            // 0..63
    w2t[c * HDIM + k] = W2[k * VDIM + c];
  }
}

// --- main: per 256-thread block: 64 pairs. Each wave: 16 pairs (16 a-rows +
//     16 b-rows), A-frags direct from global (fp32->bf16 in-register),
//     B-frags from pre-swizzled w1s (L2-resident), 25 K-steps x 8 MFMA.
__global__ __launch_bounds__(256, 4)
void qcm_kernel(const float* __restrict__ img_a, const float* __restrict__ img_b,
                const float* __restrict__ b1,    const float* __restrict__ b2,
                const unsigned short* __restrict__ w1s,
                const float* __restrict__ w2t,
                float* __restrict__ out) {
  __shared__ __attribute__((aligned(16))) float lds_h[128][68];

  const int tid  = threadIdx.x;
  const int wave = tid >> 6;
  const int lane = tid & 63;
  const int m    = lane & 15;     // A-frag row / C-frag col
  const int quad = lane >> 4;
  const int p0   = blockIdx.x * 64 + wave * 16;   // first pair for this wave

  const float* rowA = img_a + (size_t)(p0 + m) * KDIM;
  const float* rowB = img_b + (size_t)(p0 + m) * KDIM;
  const int koff = quad * 8;      // A-frag k-offset: k = quad*8 + j

  f32x4 accA[4], accB[4];
  #pragma unroll
  for (int t = 0; t < 4; ++t) {
    accA[t][0] = accA[t][1] = accA[t][2] = accA[t][3] = 0.0f;
    accB[t][0] = accB[t][1] = accB[t][2] = accB[t][3] = 0.0f;
  }

  const int4* bw = (const int4*)w1s;

  // 24 full K-steps (k = 0..767)
  for (int s = 0; s < 24; ++s) {
    const int kb = s * 32 + koff;
    f32x4 xa0 = *(const f32x4*)(rowA + kb);
    f32x4 xa1 = *(const f32x4*)(rowA + kb + 4);
    f32x4 xb0 = *(const f32x4*)(rowB + kb);
    f32x4 xb1 = *(const f32x4*)(rowB + kb + 4);
    bf16x8 fa = cvt8(xa0, xa1);
    bf16x8 fb = cvt8(xb0, xb1);
    const int4* bp = bw + (s * 4) * 64 + lane;
    #pragma unroll
    for (int t = 0; t < 4; ++t) {
      int4 raw = bp[t * 64];
      bf16x8 wf = __builtin_bit_cast(bf16x8, raw);
      accA[t] = __builtin_amdgcn_mfma_f32_16x16x32_bf16(fa, wf, accA[t], 0, 0, 0);
      accB[t] = __builtin_amdgcn_mfma_f32_16x16x32_bf16(fb, wf, accB[t], 0, 0, 0);
    }
  }

  // tail K-step (k = 768..799): quads 2,3 are past 784 -> zero (w1s also 0 there)
  {
    const int kb = 24 * 32 + koff;
    f32x4 z; z[0] = z[1] = z[2] = z[3] = 0.0f;
    f32x4 xa0 = z, xa1 = z, xb0 = z, xb1 = z;
    if (quad < 2) {
      xa0 = *(const f32x4*)(rowA + kb);
      xa1 = *(const f32x4*)(rowA + kb + 4);
      xb0 = *(const f32x4*)(rowB + kb);
      xb1 = *(const f32x4*)(rowB + kb + 4);
    }
    bf16x8 fa = cvt8(xa0, xa1);
    bf16x8 fb = cvt8(xb0, xb1);
    const int4* bp = bw + (24 * 4) * 64 + lane;
    #pragma unroll
    for (int t = 0; t < 4; ++t) {
      int4 raw = bp[t * 64];
      bf16x8 wf = __builtin_bit_cast(bf16x8, raw);
      accA[t] = __builtin_amdgcn_mfma_f32_16x16x32_bf16(fa, wf, accA[t], 0, 0, 0);
      accB[t] = __builtin_amdgcn_mfma_f32_16x16x32_bf16(fb, wf, accB[t], 0, 0, 0);
    }
  }

  // epilogue: bias + relu, park h in LDS (C-frag: row = quad*4+j, col = lane&15)
  #pragma unroll
  for (int t = 0; t < 4; ++t) {
    float bias = b1[t * 16 + m];
    const int ra = wave * 32;        // a-rows base
    #pragma unroll
    for (int j = 0; j < 4; ++j) {
      float ha = fmaxf(accA[t][j] + bias, 0.0f);
      float hb = fmaxf(accB[t][j] + bias, 0.0f);
      lds_h[ra +      quad * 4 + j][t * 16 + m] = ha;
      lds_h[ra + 16 + quad * 4 + j][t * 16 + m] = hb;
    }
  }
  __syncthreads();

  // phase 2: 4 threads per pair; each computes 4 of the 16 z-columns for a and b
  const int p = tid >> 2;            // 0..63 local pair
  const int q = tid & 3;
  const int wsrc = p >> 4;
  const int r = p & 15;
  const float* ha_row = lds_h[wsrc * 32 + r];
  const float* hb_row = lds_h[wsrc * 32 + 16 + r];

  float za[4], zb[4];
  #pragma unroll
  for (int i = 0; i < 4; ++i) { za[i] = b2[q * 4 + i]; zb[i] = za[i]; }

  for (int k = 0; k < HDIM; k += 4) {
    f32x4 ha = *(const f32x4*)(ha_row + k);
    f32x4 hb = *(const f32x4*)(hb_row + k);
    #pragma unroll
    for (int i = 0; i < 4; ++i) {
      f32x4 wv = *(const f32x4*)(w2t + (q * 4 + i) * HDIM + k);
      za[i] += ha[0] * wv[0] + ha[1] * wv[1] + ha[2] * wv[2] + ha[3] * wv[3];
      zb[i] += hb[0] * wv[0] + hb[1] * wv[1] + hb[2] * wv[2] + hb[3] * wv[3];
    }
  }

  float d = 0.0f, na2 = 0.0f, nb2 = 0.0f;
  #pragma unroll
  for (int i = 0; i < 4; ++i) {
    float ua = tanh_fast(za[i]);
    float ub = tanh_fast(zb[i]);
    d   += ua * ub;
    na2 += ua * ua;
    nb2 += ub * ub;
  }
  // reduce across the 4 threads of this pair (adjacent lanes)
  d   += __shfl_xor(d, 1);   d   += __shfl_xor(d, 2);
  na2 += __shfl_xor(na2, 1); na2 += __shfl_xor(na2, 2);
  nb2 += __shfl_xor(nb2, 1); nb2 += __shfl_xor(nb2, 2);

  if (q == 0) {
    float den = fmaxf(sqrtf(na2), 1e-8f) * fmaxf(sqrtf(nb2), 1e-8f);
    float ov  = d / den;
    float fid = ov * ov;
    out[blockIdx.x * 64 + p] = fminf(fid, 1.0f);
  }
}

extern "C" void kernel_launch(void* const* d_in, const int* in_sizes, int n_in,
                              void* d_out, int out_size, void* d_ws, size_t ws_size,
                              hipStream_t stream) {
  const float* img_a = (const float*)d_in[0];
  const float* img_b = (const float*)d_in[1];
  const float* W1    = (const float*)d_in[2];
  const float* b1    = (const float*)d_in[3];
  const float* W2    = (const float*)d_in[4];
  const float* b2    = (const float*)d_in[5];
  // d_in[6] = theta: unused — the circuit is unitary, fidelity is invariant.

  unsigned short* w1s = (unsigned short*)d_ws;
  float* w2t = (float*)((char*)d_ws + W1S_BYTES);

  prep_kernel<<<(W1S_ELEMS + 255) / 256, 256, 0, stream>>>(W1, W2, w1s, w2t);

  const int n_pairs = out_size;              // 65536
  qcm_kernel<<<n_pairs / 64, 256, 0, stream>>>(img_a, img_b, b1, b2, w1s, w2t,
                                               (float*)d_out);
}

// Round 2
// 439.149 us; speedup vs baseline: 1.0209x; 1.0209x over previous
//
#include <hip/hip_runtime.h>

// =============================================================================
// QuantumContrastiveModel — mathematical reduction:
//   StronglyEntanglingLayers is a fixed 16x16 UNITARY applied to BOTH states;
//   fidelity |<U va|U vb>|^2 = (va.vb)^2 — the circuit cancels, theta unused.
//   With u = tanh(relu(x@W1+b1)@W2+b2):
//     fid = clip( (ua.ub)^2 / (max(|ua|,1e-8)*max(|ub|,1e-8))^2, 0, 1 )
//   R1: 170us, latency-bound (vmcnt(0) drain per K-iter, all pipes <10%).
//   R2: depth-1 A-prefetch software pipeline + B-loads at iter top + bf16 LDS
//       h-staging (18.4KB) so LDS never caps occupancy.
// =============================================================================

#define KDIM   784
#define HDIM   64
#define KSTEPS 25                        // ceil(784/32); last step zero-padded
#define W1S_ELEMS (KSTEPS * 4 * 64 * 8)  // 51200 bf16 in B-fragment order
#define W1S_BYTES (W1S_ELEMS * 2)        // 102400 bytes

typedef float  f32x4  __attribute__((ext_vector_type(4)));
typedef short  bf16x8 __attribute__((ext_vector_type(8)));

__device__ __forceinline__ unsigned short f2bf(float f) {
  unsigned u = __float_as_uint(f);
  u += 0x7fffu + ((u >> 16) & 1u);       // round-to-nearest-even
  return (unsigned short)(u >> 16);
}

__device__ __forceinline__ float bf2f(unsigned short h) {
  return __uint_as_float(((unsigned)h) << 16);
}

__device__ __forceinline__ bf16x8 cvt8(f32x4 lo, f32x4 hi) {
  bf16x8 r;
  r[0] = (short)f2bf(lo[0]); r[1] = (short)f2bf(lo[1]);
  r[2] = (short)f2bf(lo[2]); r[3] = (short)f2bf(lo[3]);
  r[4] = (short)f2bf(hi[0]); r[5] = (short)f2bf(hi[1]);
  r[6] = (short)f2bf(hi[2]); r[7] = (short)f2bf(hi[3]);
  return r;
}

__device__ __forceinline__ float tanh_fast(float x) {
  float e = __expf(2.0f * x);
  return 1.0f - 2.0f / (e + 1.0f);       // exact limits at +-inf
}

// --- prep: W1 (784x64 f32) -> bf16 in MFMA B-fragment order, K padded to 800;
//           W2 (64x16) -> transposed (16x64) f32.
__global__ __launch_bounds__(256)
void prep_kernel(const float* __restrict__ W1, const float* __restrict__ W2,
                 unsigned short* __restrict__ w1s, float* __restrict__ w2t) {
  int tid = blockIdx.x * 256 + threadIdx.x;
  if (tid < W1S_ELEMS) {
    int j  = tid & 7;            // element within 8-wide fragment
    int l  = (tid >> 3) & 63;    // lane
    int st = tid >> 9;           // s*4 + t
    int s  = st >> 2;
    int t  = st & 3;
    int k  = s * 32 + (l >> 4) * 8 + j;   // B[k][n]: k = quad*8+j
    int n  = t * 16 + (l & 15);           //          n = lane&15
    float v = (k < KDIM) ? W1[k * HDIM + n] : 0.0f;
    w1s[tid] = f2bf(v);
  }
  if (tid < HDIM * 16) {
    int c = tid >> 6;            // 0..15
    int k = tid & 63;            // 0..63
    w2t[c * HDIM + k] = W2[k * 16 + c];
  }
}

// --- main: 64 pairs/block; each wave: 16 pairs (16 a-rows + 16 b-rows).
//     Depth-1 software pipeline: A-loads for s+1 in flight while computing s.
__global__ __launch_bounds__(256, 4)
void qcm_kernel(const float* __restrict__ img_a, const float* __restrict__ img_b,
                const float* __restrict__ b1,    const float* __restrict__ b2,
                const unsigned short* __restrict__ w1s,
                const float* __restrict__ w2t,
                float* __restrict__ out) {
  __shared__ __attribute__((aligned(16))) unsigned short lds_h[128][72]; // 18.4KB

  const int tid  = threadIdx.x;
  const int wave = tid >> 6;
  const int lane = tid & 63;
  const int m    = lane & 15;     // A-frag row / C-frag col
  const int quad = lane >> 4;
  const int p0   = blockIdx.x * 64 + wave * 16;

  const float* rowA = img_a + (size_t)(p0 + m) * KDIM;
  const float* rowB = img_b + (size_t)(p0 + m) * KDIM;
  const int koff = quad * 8;      // A-frag k-offset: k = quad*8 + j

  f32x4 accA[4], accB[4];
  #pragma unroll
  for (int t = 0; t < 4; ++t) {
    accA[t][0] = accA[t][1] = accA[t][2] = accA[t][3] = 0.0f;
    accB[t][0] = accB[t][1] = accB[t][2] = accB[t][3] = 0.0f;
  }

  const int4* bwl = (const int4*)w1s + lane;
  f32x4 z4; z4[0] = z4[1] = z4[2] = z4[3] = 0.0f;

  // prologue: load s=0
  f32x4 c0 = *(const f32x4*)(rowA + koff);
  f32x4 c1 = *(const f32x4*)(rowA + koff + 4);
  f32x4 c2 = *(const f32x4*)(rowB + koff);
  f32x4 c3 = *(const f32x4*)(rowB + koff + 4);

  for (int s = 0; s < KSTEPS; ++s) {
    // B frags for s — issue first; cvt VALU below covers their L2 latency
    int4 w0 = bwl[s * 256];
    int4 w1 = bwl[s * 256 + 64];
    int4 w2 = bwl[s * 256 + 128];
    int4 w3 = bwl[s * 256 + 192];

    // prefetch A for s+1 (depth-1 pipeline)
    f32x4 n0 = z4, n1 = z4, n2 = z4, n3 = z4;
    if (s < 23) {
      const int kb = (s + 1) * 32 + koff;
      n0 = *(const f32x4*)(rowA + kb);
      n1 = *(const f32x4*)(rowA + kb + 4);
      n2 = *(const f32x4*)(rowB + kb);
      n3 = *(const f32x4*)(rowB + kb + 4);
    } else if (s == 23) {
      // tail step: k = 768..799, quads 2,3 past 784 -> stay zero (w1s 0 too)
      if (quad < 2) {
        const int kb = 768 + koff;
        n0 = *(const f32x4*)(rowA + kb);
        n1 = *(const f32x4*)(rowA + kb + 4);
        n2 = *(const f32x4*)(rowB + kb);
        n3 = *(const f32x4*)(rowB + kb + 4);
      }
    }

    bf16x8 fa = cvt8(c0, c1);
    bf16x8 fb = cvt8(c2, c3);

    bf16x8 wf0 = __builtin_bit_cast(bf16x8, w0);
    bf16x8 wf1 = __builtin_bit_cast(bf16x8, w1);
    bf16x8 wf2 = __builtin_bit_cast(bf16x8, w2);
    bf16x8 wf3 = __builtin_bit_cast(bf16x8, w3);
    accA[0] = __builtin_amdgcn_mfma_f32_16x16x32_bf16(fa, wf0, accA[0], 0, 0, 0);
    accB[0] = __builtin_amdgcn_mfma_f32_16x16x32_bf16(fb, wf0, accB[0], 0, 0, 0);
    accA[1] = __builtin_amdgcn_mfma_f32_16x16x32_bf16(fa, wf1, accA[1], 0, 0, 0);
    accB[1] = __builtin_amdgcn_mfma_f32_16x16x32_bf16(fb, wf1, accB[1], 0, 0, 0);
    accA[2] = __builtin_amdgcn_mfma_f32_16x16x32_bf16(fa, wf2, accA[2], 0, 0, 0);
    accB[2] = __builtin_amdgcn_mfma_f32_16x16x32_bf16(fb, wf2, accB[2], 0, 0, 0);
    accA[3] = __builtin_amdgcn_mfma_f32_16x16x32_bf16(fa, wf3, accA[3], 0, 0, 0);
    accB[3] = __builtin_amdgcn_mfma_f32_16x16x32_bf16(fb, wf3, accB[3], 0, 0, 0);

    c0 = n0; c1 = n1; c2 = n2; c3 = n3;
  }

  // epilogue: bias + relu, park h in LDS as bf16 (C-frag: row=quad*4+j, col=lane&15)
  #pragma unroll
  for (int t = 0; t < 4; ++t) {
    float bias = b1[t * 16 + m];
    const int ra = wave * 32;
    #pragma unroll
    for (int j = 0; j < 4; ++j) {
      float ha = fmaxf(accA[t][j] + bias, 0.0f);
      float hb = fmaxf(accB[t][j] + bias, 0.0f);
      lds_h[ra +      quad * 4 + j][t * 16 + m] = f2bf(ha);
      lds_h[ra + 16 + quad * 4 + j][t * 16 + m] = f2bf(hb);
    }
  }
  __syncthreads();

  // phase 2: 4 threads per pair; each computes 4 of the 16 z-columns for a and b
  const int p = tid >> 2;            // 0..63 local pair
  const int q = tid & 3;
  const int wsrc = p >> 4;
  const int r = p & 15;
  const unsigned short* ha_row = &lds_h[wsrc * 32 + r][0];
  const unsigned short* hb_row = &lds_h[wsrc * 32 + 16 + r][0];

  float za[4], zb[4];
  #pragma unroll
  for (int i = 0; i < 4; ++i) { za[i] = b2[q * 4 + i]; zb[i] = za[i]; }

  for (int k = 0; k < HDIM; k += 4) {
    uint2 ua = *(const uint2*)(ha_row + k);
    uint2 ub = *(const uint2*)(hb_row + k);
    float a0 = bf2f((unsigned short)(ua.x & 0xffff));
    float a1 = bf2f((unsigned short)(ua.x >> 16));
    float a2 = bf2f((unsigned short)(ua.y & 0xffff));
    float a3 = bf2f((unsigned short)(ua.y >> 16));
    float b0v = bf2f((unsigned short)(ub.x & 0xffff));
    float b1v = bf2f((unsigned short)(ub.x >> 16));
    float b2v = bf2f((unsigned short)(ub.y & 0xffff));
    float b3v = bf2f((unsigned short)(ub.y >> 16));
    #pragma unroll
    for (int i = 0; i < 4; ++i) {
      f32x4 wv = *(const f32x4*)(w2t + (q * 4 + i) * HDIM + k);
      za[i] += a0 * wv[0] + a1 * wv[1] + a2 * wv[2] + a3 * wv[3];
      zb[i] += b0v * wv[0] + b1v * wv[1] + b2v * wv[2] + b3v * wv[3];
    }
  }

  float d = 0.0f, na2 = 0.0f, nb2 = 0.0f;
  #pragma unroll
  for (int i = 0; i < 4; ++i) {
    float ua = tanh_fast(za[i]);
    float ub = tanh_fast(zb[i]);
    d   += ua * ub;
    na2 += ua * ua;
    nb2 += ub * ub;
  }
  d   += __shfl_xor(d, 1);   d   += __shfl_xor(d, 2);
  na2 += __shfl_xor(na2, 1); na2 += __shfl_xor(na2, 2);
  nb2 += __shfl_xor(nb2, 1); nb2 += __shfl_xor(nb2, 2);

  if (q == 0) {
    float den = fmaxf(sqrtf(na2), 1e-8f) * fmaxf(sqrtf(nb2), 1e-8f);
    float ov  = d / den;
    float fid = ov * ov;
    out[blockIdx.x * 64 + p] = fminf(fid, 1.0f);
  }
}

extern "C" void kernel_launch(void* const* d_in, const int* in_sizes, int n_in,
                              void* d_out, int out_size, void* d_ws, size_t ws_size,
                              hipStream_t stream) {
  const float* img_a = (const float*)d_in[0];
  const float* img_b = (const float*)d_in[1];
  const float* W1    = (const float*)d_in[2];
  const float* b1    = (const float*)d_in[3];
  const float* W2    = (const float*)d_in[4];
  const float* b2    = (const float*)d_in[5];
  // d_in[6] = theta: unused — the circuit is unitary, fidelity is invariant.

  unsigned short* w1s = (unsigned short*)d_ws;
  float* w2t = (float*)((char*)d_ws + W1S_BYTES);

  prep_kernel<<<(W1S_ELEMS + 255) / 256, 256, 0, stream>>>(W1, W2, w1s, w2t);

  const int n_pairs = out_size;              // 65536
  qcm_kernel<<<n_pairs / 64, 256, 0, stream>>>(img_a, img_b, b1, b2, w1s, w2t,
                                               (float*)d_out);
}